// Round 8
// baseline (915.454 us; speedup 1.0000x reference)
//
#include <hip/hip_runtime.h>
#include <hip/hip_bf16.h>
#include <math.h>

#define HID 128
#define HEADS 8
#define INDIM 64

typedef _Float16 f16x8 __attribute__((ext_vector_type(8)));
typedef _Float16 f16x4 __attribute__((ext_vector_type(4)));
typedef _Float16 f16x2 __attribute__((ext_vector_type(2)));
typedef float f32x4 __attribute__((ext_vector_type(4)));

union F16x8u { f16x8 v; int4 i; f16x2 p[4]; };

__device__ __forceinline__ float fast_tanh(float x) {
    return 1.f - 2.f / (__expf(2.f * x) + 1.f);
}

#if defined(__has_builtin)
#if __has_builtin(__builtin_amdgcn_fdot2)
#define HAVE_FDOT2 1
#endif
#endif

// ================= prologue: deg count + weight transposes + gstart + hgZ zero ==========
__global__ void prologue_kernel(const int* __restrict__ ei, int* __restrict__ deg,
                                const float* __restrict__ emb_W, const float* __restrict__ gat_W,
                                const float* __restrict__ ga_W1, _Float16* __restrict__ wt_emb,
                                _Float16* __restrict__ wt_gat, _Float16* __restrict__ wt_ga1,
                                const int* __restrict__ batch, int* __restrict__ gstart,
                                float* __restrict__ hgZ,
                                int E, int EE, int N, int G) {
    int i = blockIdx.x * blockDim.x + threadIdx.x;
    if (i < EE) {
        int dst = (i < E) ? ei[E + i] : (i - E);
        atomicAdd(&deg[dst], 1);
    }
    if (i < 8192) {                       // emb_W [64][128]
        int k = i >> 7, n = i & 127;
        wt_emb[n * 64 + k] = (_Float16)emb_W[i];
    } else if (i < 8192 + 49152) {        // gat_W [3][128][128]
        int j = i - 8192;
        int l = j >> 14, r = j & 16383;
        int k = r >> 7, n = r & 127;
        wt_gat[l * 16384 + n * 128 + k] = (_Float16)gat_W[j];
    } else if (i < 73728) {               // ga_W1 [128][128]
        int j = i - 57344;
        int k = j >> 7, n = j & 127;
        wt_ga1[n * 128 + k] = (_Float16)ga_W1[j];
    } else if (i < 73728 + 129) {         // hgZ zero
        hgZ[i - 73728] = 0.f;
    }
    if (i >= 100000 && i - 100000 <= G) {
        int g = i - 100000;
        int lo = 0, hi = N;
        while (lo < hi) {
            int mid = (lo + hi) >> 1;
            if (batch[mid] < g) lo = mid + 1; else hi = mid;
        }
        gstart[g] = lo;
    }
}

// ================= R2-verified MFMA projection kernel (2 row-tiles per block) ==========
// mode 0: A=f32 x (convert in staging), epilogue bias+ntype_emb -> h16
// mode 1: A=h16, epilogue hp16 + als/ald
// Extra blocks (>= PB): task 1 = rowptr build; task 2 = scatter (grid-stride)
__global__ __launch_bounds__(256) void mfma_proj_kernel(
    int mode, int K, int N,
    const _Float16* __restrict__ A16, const float* __restrict__ Af32,
    const _Float16* __restrict__ Wt,
    const float* __restrict__ bias, const float* __restrict__ nemb,
    const int* __restrict__ ntypes, _Float16* __restrict__ h16out,
    const float* __restrict__ asrc, const float* __restrict__ adst,
    _Float16* __restrict__ hp_out, float* __restrict__ als, float* __restrict__ ald,
    int PB, int task, const int* __restrict__ ei2,
    const int* __restrict__ degc,
    int* __restrict__ rowptrw, int* __restrict__ woffw, int* __restrict__ esrcw,
    int E2, int EE2)
{
    __shared__ _Float16 w_lds[128 * 136];   // 34.8 KB
    __shared__ _Float16 a_lds[64 * 136];    // 17.4 KB
    int t = threadIdx.x;

    if ((int)blockIdx.x >= PB) {
        if (task == 1) {
            // ---- rowptr: exclusive prefix over deg (direct strided prefix) ----
            int b = (int)blockIdx.x - PB;
            int i = b * 256 + t;
            int v = (i < N) ? degc[i] : 0;
            int pe = 0;
            for (int j = t; j < (b << 8); j += 256) pe += degc[j];
#pragma unroll
            for (int m = 32; m >= 1; m >>= 1) pe += __shfl_xor(pe, m, 64);
            int* itmp  = (int*)a_lds;
            int* itmp2 = itmp + 256;
            itmp[t] = v;
            if ((t & 63) == 0) itmp2[t >> 6] = pe;
            __syncthreads();
#pragma unroll
            for (int off = 1; off < 256; off <<= 1) {
                int x = (t >= off) ? itmp[t - off] : 0;
                __syncthreads();
                itmp[t] += x;
                __syncthreads();
            }
            pe = itmp2[0] + itmp2[1] + itmp2[2] + itmp2[3];
            int excl = itmp[t] - v + pe;
            if (i < N) { rowptrw[i] = excl; woffw[i] = excl; }
            if (b == 0 && t == 0) rowptrw[N] = EE2;
        } else {
            // ---- scatter: CSR column fill (grid-stride) ----
            int sb = (int)blockIdx.x - PB;
            int stride = ((int)gridDim.x - PB) << 8;
            for (int e = sb * 256 + t; e < EE2; e += stride) {
                int src, dst;
                if (e < E2) { src = ei2[e]; dst = ei2[E2 + e]; } else { src = dst = e - E2; }
                int slot = atomicAdd(&woffw[dst], 1);
                esrcw[slot] = src;
            }
        }
        return;
    }

    int KP = K + 8;
    int K8 = K >> 3;

    // stage W once (coalesced)
    for (int i = t; i < 128 * K8; i += 256) {
        int row = i / K8, c8 = i - row * K8;
        *(f16x8*)&w_lds[row * KP + 8 * c8] = *(const f16x8*)&Wt[(size_t)row * K + 8 * c8];
    }

    int lane = t & 63, wv = t >> 6;
    int l15 = lane & 15, quad = lane >> 4;

    for (int tile = 0; tile < 2; ++tile) {
        int n0 = blockIdx.x * 128 + tile * 64;
        if (n0 >= N) break;
        __syncthreads();
        if (mode == 0) {
            for (int i = t; i < 64 * K8; i += 256) {
                int row = i / K8, c8 = i - row * K8;
                f16x8 v = {};
                int n = n0 + row;
                if (n < N) {
                    const float4* ptr = (const float4*)&Af32[(size_t)n * K + 8 * c8];
                    float4 a = ptr[0], b4 = ptr[1];
                    v[0] = (_Float16)a.x; v[1] = (_Float16)a.y;
                    v[2] = (_Float16)a.z; v[3] = (_Float16)a.w;
                    v[4] = (_Float16)b4.x; v[5] = (_Float16)b4.y;
                    v[6] = (_Float16)b4.z; v[7] = (_Float16)b4.w;
                }
                *(f16x8*)&a_lds[row * KP + 8 * c8] = v;
            }
        } else {
            for (int i = t; i < 64 * K8; i += 256) {
                int row = i / K8, c8 = i - row * K8;
                f16x8 v = {};
                if (n0 + row < N) v = *(const f16x8*)&A16[(size_t)(n0 + row) * K + 8 * c8];
                *(f16x8*)&a_lds[row * KP + 8 * c8] = v;
            }
        }
        __syncthreads();

        f32x4 acc[8];
#pragma unroll
        for (int c = 0; c < 8; ++c) acc[c] = (f32x4){0.f, 0.f, 0.f, 0.f};

        int ksteps = K >> 5;
        for (int kk = 0; kk < ksteps; ++kk) {
            f16x8 af = *(const f16x8*)&a_lds[(wv * 16 + l15) * KP + kk * 32 + quad * 8];
#pragma unroll
            for (int c = 0; c < 8; ++c) {
                f16x8 bf = *(const f16x8*)&w_lds[(c * 16 + l15) * KP + kk * 32 + quad * 8];
                acc[c] = __builtin_amdgcn_mfma_f32_16x16x32_f16(af, bf, acc[c], 0, 0, 0);
            }
        }

        // C layout: row = wv*16 + quad*4 + r, col = c*16 + l15
        if (mode == 0) {
            float bv[8];
#pragma unroll
            for (int c = 0; c < 8; ++c) bv[c] = bias[c * 16 + l15];
            __syncthreads();
#pragma unroll
            for (int r = 0; r < 4; ++r) {
                int n = n0 + wv * 16 + quad * 4 + r;
                int nt = (n < N) ? ntypes[n] : 0;
#pragma unroll
                for (int c = 0; c < 8; ++c)
                    a_lds[(wv * 16 + quad * 4 + r) * 136 + c * 16 + l15] =
                        (_Float16)(acc[c][r] + bv[c] + nemb[nt * HID + c * 16 + l15]);
            }
            __syncthreads();
            for (int i = t; i < 64 * 16; i += 256) {
                int row = i >> 4, c8 = i & 15;
                int n = n0 + row;
                if (n < N) *(f16x8*)&h16out[(size_t)n * HID + 8 * c8] = *(const f16x8*)&a_lds[row * 136 + 8 * c8];
            }
        } else {
            __syncthreads();
#pragma unroll
            for (int c = 0; c < 8; ++c)
#pragma unroll
                for (int r = 0; r < 4; ++r)
                    a_lds[(wv * 16 + quad * 4 + r) * 136 + c * 16 + l15] = (_Float16)acc[c][r];
            __syncthreads();
            for (int i = t; i < 64 * 16; i += 256) {
                int row = i >> 4, c8 = i & 15;
                int n = n0 + row;
                if (n < N) *(f16x8*)&hp_out[(size_t)n * HID + 8 * c8] = *(const f16x8*)&a_lds[row * 136 + 8 * c8];
            }
            for (int task2 = t; task2 < 512; task2 += 256) {
                int row = task2 >> 3, hd = task2 & 7;
                int n = n0 + row;
                if (n >= N) continue;
                f16x8 v0 = *(const f16x8*)&a_lds[row * 136 + hd * 16];
                f16x8 v1 = *(const f16x8*)&a_lds[row * 136 + hd * 16 + 8];
                float va = 0.f, vd = 0.f;
#pragma unroll
                for (int j = 0; j < 8; ++j) {
                    va += (float)v0[j] * asrc[hd * 16 + j] + (float)v1[j] * asrc[hd * 16 + 8 + j];
                    vd += (float)v0[j] * adst[hd * 16 + j] + (float)v1[j] * adst[hd * 16 + 8 + j];
                }
                als[n * HEADS + hd] = va;
                ald[n * HEADS + hd] = vd;
            }
        }
    }
}

// ================= fused aggregate + register-only next-proj epilogue ===================
// Gather/LN identical to the R2-verified aggregate. After LN, the wave holds node n's
// full h row in registers (cg lanes x 8 ch). Epilogue computes hp_next = h @ W (2 output
// channels per lane via shfl-broadcast + L1-hot Wt reads) — no LDS, no extra dispatch,
// no h16 re-read. mode 1: GAT proj (hp/als/ald out, double-buffered). mode 2: score.
__global__ void agg_proj_kernel(
    const int* __restrict__ rowptr, const int* __restrict__ esrc,
    const float* __restrict__ als_in, const float* __restrict__ ald_in,
    const _Float16* __restrict__ hp_in,
    const float* __restrict__ gb, const float* __restrict__ lg, const float* __restrict__ lb,
    _Float16* __restrict__ h16,
    int mode, const _Float16* __restrict__ Wt,
    const float* __restrict__ asrc, const float* __restrict__ adst,
    _Float16* __restrict__ hp_out, float* __restrict__ als_out, float* __restrict__ ald_out,
    const float* __restrict__ b1, const float* __restrict__ w2f, const float* __restrict__ b2,
    float* __restrict__ escore, int N)
{
    int wave = threadIdx.x >> 6;
    int lane = threadIdx.x & 63;
    int n = blockIdx.x * 4 + wave;
    if (n >= N) return;
    int esub = lane >> 4;
    int cg = lane & 15;
    int hd = cg >> 1;
    float adv = ald_in[n * HEADS + hd];
    int row = rowptr[n], end = rowptr[n + 1];
    int last = end - 1;
    float acc[8] = {0.f, 0.f, 0.f, 0.f, 0.f, 0.f, 0.f, 0.f};
    float sw = 0.f;
    for (int base = row; base < end; base += 16) {
        int iA = base + esub;
        int iB = iA + 4, iC = iA + 8, iD = iA + 12;
        int cA = iA <= last ? iA : last;
        int cB = iB <= last ? iB : last;
        int cC = iC <= last ? iC : last;
        int cD = iD <= last ? iD : last;
        int sA = esrc[cA], sB = esrc[cB], sC = esrc[cC], sD = esrc[cD];
        f16x8 pA = *(const f16x8*)&hp_in[(size_t)sA * HID + cg * 8];
        f16x8 pB = *(const f16x8*)&hp_in[(size_t)sB * HID + cg * 8];
        f16x8 pC = *(const f16x8*)&hp_in[(size_t)sC * HID + cg * 8];
        f16x8 pD = *(const f16x8*)&hp_in[(size_t)sD * HID + cg * 8];
        float aA = als_in[sA * HEADS + hd];
        float aB = als_in[sB * HEADS + hd];
        float aC = als_in[sC * HEADS + hd];
        float aD = als_in[sD * HEADS + hd];
        float lA = aA + adv; lA = lA > 0.f ? lA : 0.2f * lA;
        float lB = aB + adv; lB = lB > 0.f ? lB : 0.2f * lB;
        float lC = aC + adv; lC = lC > 0.f ? lC : 0.2f * lC;
        float lD = aD + adv; lD = lD > 0.f ? lD : 0.2f * lD;
        float wA = __expf(lA) * ((iA < end) ? 1.f : 0.f);
        float wB = __expf(lB) * ((iB < end) ? 1.f : 0.f);
        float wC = __expf(lC) * ((iC < end) ? 1.f : 0.f);
        float wD = __expf(lD) * ((iD < end) ? 1.f : 0.f);
        sw += (wA + wB) + (wC + wD);
#ifdef HAVE_FDOT2
        f16x2 wAB; wAB[0] = (_Float16)wA; wAB[1] = (_Float16)wB;
        f16x2 wCD; wCD[0] = (_Float16)wC; wCD[1] = (_Float16)wD;
#pragma unroll
        for (int j = 0; j < 8; ++j) {
            f16x2 prAB; prAB[0] = pA[j]; prAB[1] = pB[j];
            f16x2 prCD; prCD[0] = pC[j]; prCD[1] = pD[j];
            acc[j] = __builtin_amdgcn_fdot2(prAB, wAB, acc[j], false);
            acc[j] = __builtin_amdgcn_fdot2(prCD, wCD, acc[j], false);
        }
#else
#pragma unroll
        for (int j = 0; j < 8; ++j)
            acc[j] += wA * (float)pA[j] + wB * (float)pB[j]
                    + wC * (float)pC[j] + wD * (float)pD[j];
#endif
    }
#pragma unroll
    for (int m = 16; m <= 32; m <<= 1) {
        sw += __shfl_xor(sw, m, 64);
#pragma unroll
        for (int j = 0; j < 8; ++j) acc[j] += __shfl_xor(acc[j], m, 64);
    }
    float inv_sw = 1.f / sw;
    float4 g0 = ((const float4*)(gb + cg * 8))[0];
    float4 g1 = ((const float4*)(gb + cg * 8))[1];
    float v[8];
    v[0] = acc[0] * inv_sw + g0.x; v[1] = acc[1] * inv_sw + g0.y;
    v[2] = acc[2] * inv_sw + g0.z; v[3] = acc[3] * inv_sw + g0.w;
    v[4] = acc[4] * inv_sw + g1.x; v[5] = acc[5] * inv_sw + g1.y;
    v[6] = acc[6] * inv_sw + g1.z; v[7] = acc[7] * inv_sw + g1.w;
    float s = 0.f;
#pragma unroll
    for (int j = 0; j < 8; ++j) s += v[j];
#pragma unroll
    for (int m = 32; m >= 1; m >>= 1) s += __shfl_xor(s, m, 64);
    float mu = s * (1.f / 512.f);
    float d[8], sq = 0.f;
#pragma unroll
    for (int j = 0; j < 8; ++j) { d[j] = v[j] - mu; sq += d[j] * d[j]; }
#pragma unroll
    for (int m = 32; m >= 1; m >>= 1) sq += __shfl_xor(sq, m, 64);
    float inv = rsqrtf(sq * (1.f / 512.f) + 1e-5f);
    float4 lg0 = ((const float4*)(lg + cg * 8))[0];
    float4 lg1 = ((const float4*)(lg + cg * 8))[1];
    float4 lb0 = ((const float4*)(lb + cg * 8))[0];
    float4 lb1 = ((const float4*)(lb + cg * 8))[1];
    float lgv[8] = {lg0.x, lg0.y, lg0.z, lg0.w, lg1.x, lg1.y, lg1.z, lg1.w};
    float lbv[8] = {lb0.x, lb0.y, lb0.z, lb0.w, lb1.x, lb1.y, lb1.z, lb1.w};
    F16x8u hu;
    {
        f16x8 hold = *(const f16x8*)&h16[(size_t)n * HID + cg * 8];
#pragma unroll
        for (int j = 0; j < 8; ++j) {
            float r = d[j] * inv * lgv[j] + lbv[j] + (float)hold[j];
            hu.v[j] = (_Float16)(r > 0.f ? r : 0.f);
        }
    }
    if (esub == 0) *(f16x8*)&h16[(size_t)n * HID + cg * 8] = hu.v;

    // ---- register-only projection epilogue: out[c0], out[c0+1] for c0 = 2*lane ----
    int c0 = lane << 1;
    float o0 = 0.f, o1 = 0.f;
#pragma unroll
    for (int sc = 0; sc < 16; ++sc) {
        F16x8u hh;
        hh.i.x = __shfl(hu.i.x, sc, 64);
        hh.i.y = __shfl(hu.i.y, sc, 64);
        hh.i.z = __shfl(hu.i.z, sc, 64);
        hh.i.w = __shfl(hu.i.w, sc, 64);
        F16x8u w0u, w1u;
        w0u.v = *(const f16x8*)&Wt[(size_t)c0 * HID + sc * 8];
        w1u.v = *(const f16x8*)&Wt[(size_t)(c0 + 1) * HID + sc * 8];
#ifdef HAVE_FDOT2
#pragma unroll
        for (int j = 0; j < 4; ++j) {
            o0 = __builtin_amdgcn_fdot2(hh.p[j], w0u.p[j], o0, false);
            o1 = __builtin_amdgcn_fdot2(hh.p[j], w1u.p[j], o1, false);
        }
#else
#pragma unroll
        for (int j = 0; j < 8; ++j) {
            o0 += (float)hh.v[j] * (float)w0u.v[j];
            o1 += (float)hh.v[j] * (float)w1u.v[j];
        }
#endif
    }

    if (mode == 1) {
        _Float16 h0 = (_Float16)o0, h1 = (_Float16)o1;
        f16x2 hp2; hp2[0] = h0; hp2[1] = h1;
        *(f16x2*)&hp_out[(size_t)n * HID + c0] = hp2;   // 64 lanes x 4B, coalesced
        // als/ald for next layer: head of c0 is lane>>3; reduce over the 8-lane group
        float pa = (float)h0 * asrc[c0] + (float)h1 * asrc[c0 + 1];
        float pd = (float)h0 * adst[c0] + (float)h1 * adst[c0 + 1];
#pragma unroll
        for (int m = 1; m <= 4; m <<= 1) {
            pa += __shfl_xor(pa, m, 64);
            pd += __shfl_xor(pd, m, 64);
        }
        if ((lane & 7) == 0) {
            als_out[n * HEADS + (lane >> 3)] = pa;
            ald_out[n * HEADS + (lane >> 3)] = pd;
        }
    } else {
        float sc0 = fast_tanh(o0 + b1[c0]) * w2f[c0]
                  + fast_tanh(o1 + b1[c0 + 1]) * w2f[c0 + 1];
#pragma unroll
        for (int m = 32; m >= 1; m >>= 1) sc0 += __shfl_xor(sc0, m, 64);
        if (lane == 0) escore[n] = __expf(sc0 + b2[0]);
    }
}

// ================= per-graph pooling (R2-verified, 512 threads) =================
__global__ void pool_graph_kernel(const _Float16* __restrict__ h16, const float* __restrict__ escore,
                                  const int* __restrict__ gstart, float* __restrict__ sums,
                                  float* __restrict__ cnts, float* __restrict__ hgZ, int G) {
    int g = blockIdx.x;
    int t = threadIdx.x;               // 0..511
    int c = t & 127, grp = t >> 7;     // 4 groups
    int s = gstart[g], e = gstart[g + 1];
    float msum = 0.f, asum = 0.f, z = 0.f;
    for (int n = s + grp; n < e; n += 4) {
        float hv = (float)h16[(size_t)n * HID + c];
        float es = escore[n];
        msum += hv;
        asum += es * hv;
        if (c == 0) z += es;
    }
    __shared__ float sm[4][HID];
    __shared__ float sa[4][HID];
    __shared__ float sz[4];
    sm[grp][c] = msum;
    sa[grp][c] = asum;
    if (c == 0) sz[grp] = z;
    __syncthreads();
    if (t < HID) {
        float m = sm[0][t] + sm[1][t] + sm[2][t] + sm[3][t];
        float a = sa[0][t] + sa[1][t] + sa[2][t] + sa[3][t];
        sums[(size_t)g * HID + t] = m;
        atomicAdd(&hgZ[t], a);
    } else if (t == HID) {
        cnts[g] = (float)(e - s);
        atomicAdd(&hgZ[HID], sz[0] + sz[1] + sz[2] + sz[3]);
    }
}

// ================= classifier head (R2-verified) =================
__global__ void head_kernel(const float* __restrict__ hgZ, const float* __restrict__ sums,
                            const float* __restrict__ cnts, const float* __restrict__ W1,
                            const float* __restrict__ b1, const float* __restrict__ W2,
                            const float* __restrict__ b2, float* __restrict__ out, int G) {
    int g = blockIdx.x;
    int t = threadIdx.x;
    __shared__ float hr[HID];
    __shared__ float part[2];
    float Z = hgZ[HID];
    float cnt = cnts[g];
    cnt = cnt > 1.f ? cnt : 1.f;
    hr[t] = hgZ[t] / Z + sums[(size_t)g * HID + t] / cnt;
    __syncthreads();
    float acc = b1[t];
#pragma unroll 8
    for (int k = 0; k < HID; ++k) acc += hr[k] * W1[k * HID + t];
    acc = acc > 0.f ? acc : 0.f;
    float v = acc * W2[t];
#pragma unroll
    for (int m = 32; m >= 1; m >>= 1) v += __shfl_xor(v, m, 64);
    if ((t & 63) == 0) part[t >> 6] = v;
    __syncthreads();
    if (t == 0) out[g] = part[0] + part[1] + b2[0];
}

extern "C" void kernel_launch(void* const* d_in, const int* in_sizes, int n_in,
                              void* d_out, int out_size, void* d_ws, size_t ws_size,
                              hipStream_t stream) {
    const float* x        = (const float*)d_in[0];
    const int*   ei       = (const int*)d_in[1];
    const int*   ntypes   = (const int*)d_in[2];
    const int*   batch    = (const int*)d_in[3];
    const float* emb_W    = (const float*)d_in[4];
    const float* emb_b    = (const float*)d_in[5];
    const float* nemb     = (const float*)d_in[6];
    const float* gat_W    = (const float*)d_in[7];
    const float* att_src  = (const float*)d_in[8];
    const float* att_dst  = (const float*)d_in[9];
    const float* gat_b    = (const float*)d_in[10];
    const float* ln_g     = (const float*)d_in[11];
    const float* ln_b     = (const float*)d_in[12];
    const float* ga_W1    = (const float*)d_in[13];
    const float* ga_b1    = (const float*)d_in[14];
    const float* ga_W2    = (const float*)d_in[15];
    const float* ga_b2    = (const float*)d_in[16];
    const float* cls_W1   = (const float*)d_in[17];
    const float* cls_b1   = (const float*)d_in[18];
    const float* cls_W2   = (const float*)d_in[19];
    const float* cls_b2   = (const float*)d_in[20];
    float* out = (float*)d_out;

    const int N  = in_sizes[2];
    const int E  = in_sizes[1] / 2;
    const int EE = E + N;
    const int G  = out_size;
    const int NB = (N + 255) / 256;

    // ---- workspace layout ----
    float* ws      = (float*)d_ws;
    float* als_a   = ws;                               // N*8
    float* ald_a   = als_a + (size_t)N * HEADS;        // N*8
    float* als_b   = ald_a + (size_t)N * HEADS;        // N*8
    float* ald_b   = als_b + (size_t)N * HEADS;        // N*8
    float* escore  = ald_b + (size_t)N * HEADS;        // N
    float* sums    = escore + N;                       // G*128
    float* cnts    = sums + (size_t)G * HID;           // G
    float* hgZ     = cnts + G;                         // 136 (129 used)
    _Float16* h16  = (_Float16*)(hgZ + 136);           // N*128 (16B-aligned)
    _Float16* hp_a = h16 + (size_t)N * HID;            // N*128
    _Float16* hp_b = hp_a + (size_t)N * HID;           // N*128
    _Float16* wt_emb = hp_b + (size_t)N * HID;         // 128*64
    _Float16* wt_gat = wt_emb + 128 * 64;              // 3*128*128
    _Float16* wt_ga1 = wt_gat + 3 * 128 * 128;         // 128*128
    int*   rowptr  = (int*)(wt_ga1 + 128 * 128);       // N+1
    int*   woff    = rowptr + (N + 1);                 // N
    int*   deg     = woff + N;                         // N
    int*   esrc    = deg + N;                          // EE
    int*   gstart  = esrc + EE;                        // G+1

    int P1TOT = EE;
    if (P1TOT < 100000 + G + 1) P1TOT = 100000 + G + 1;

    // D1: zero deg
    hipMemsetAsync(deg, 0, (size_t)N * sizeof(int), stream);
    // D2: prologue
    prologue_kernel<<<(P1TOT + 255) / 256, 256, 0, stream>>>(
        ei, deg, emb_W, gat_W, ga_W1, wt_emb, wt_gat, wt_ga1,
        batch, gstart, hgZ, E, EE, N, G);

    const int PB = (N + 127) / 128;   // 2 tiles of 64 per block (R2 geometry)
    int SCB = 768 - PB;
    if (SCB < 128) SCB = 128;

    // D3: K1 = emb projection (mode 0) || rowptr build (task 1)
    mfma_proj_kernel<<<PB + NB, 256, 0, stream>>>(
        0, INDIM, N, nullptr, x, wt_emb, emb_b, nemb, ntypes, h16,
        nullptr, nullptr, nullptr, nullptr, nullptr,
        PB, 1, nullptr, deg, rowptr, woff, nullptr, E, EE);

    // D4: K2 = layer-0 GAT projection (mode 1) || scatter (task 2)
    mfma_proj_kernel<<<PB + SCB, 256, 0, stream>>>(
        1, HID, N, h16, nullptr, wt_gat,
        nullptr, nullptr, nullptr, nullptr,
        att_src, att_dst, hp_a, als_a, ald_a,
        PB, 2, ei, nullptr, nullptr, woff, esrc, E, EE);

    // D5: agg0 + proj1 epilogue  (reads _a, writes _b)
    agg_proj_kernel<<<(N + 3) / 4, 256, 0, stream>>>(
        rowptr, esrc, als_a, ald_a, hp_a,
        gat_b, ln_g, ln_b, h16,
        1, wt_gat + 16384, att_src + HID, att_dst + HID,
        hp_b, als_b, ald_b,
        nullptr, nullptr, nullptr, nullptr, N);

    // D6: agg1 + proj2 epilogue  (reads _b, writes _a)
    agg_proj_kernel<<<(N + 3) / 4, 256, 0, stream>>>(
        rowptr, esrc, als_b, ald_b, hp_b,
        gat_b + HID, ln_g + HID, ln_b + HID, h16,
        1, wt_gat + 32768, att_src + 2 * HID, att_dst + 2 * HID,
        hp_a, als_a, ald_a,
        nullptr, nullptr, nullptr, nullptr, N);

    // D7: agg2 + score epilogue  (reads _a, writes escore)
    agg_proj_kernel<<<(N + 3) / 4, 256, 0, stream>>>(
        rowptr, esrc, als_a, ald_a, hp_a,
        gat_b + 2 * HID, ln_g + 2 * HID, ln_b + 2 * HID, h16,
        2, wt_ga1, nullptr, nullptr,
        nullptr, nullptr, nullptr,
        ga_b1, ga_W2, ga_b2, escore, N);

    // D8/D9: pooling + head
    pool_graph_kernel<<<G, 512, 0, stream>>>(h16, escore, gstart, sums, cnts, hgZ, G);
    head_kernel<<<G, 128, 0, stream>>>(hgZ, sums, cnts, cls_W1, cls_b1, cls_W2, cls_b2, out, G);
}

// Round 9
// 406.762 us; speedup vs baseline: 2.2506x; 2.2506x over previous
//
#include <hip/hip_runtime.h>
#include <hip/hip_bf16.h>
#include <math.h>

#define HID 128
#define HEADS 8
#define INDIM 64

typedef _Float16 f16x8 __attribute__((ext_vector_type(8)));
typedef _Float16 f16x4 __attribute__((ext_vector_type(4)));
typedef _Float16 f16x2 __attribute__((ext_vector_type(2)));
typedef float f32x4 __attribute__((ext_vector_type(4)));

__device__ __forceinline__ float fast_tanh(float x) {
    return 1.f - 2.f / (__expf(2.f * x) + 1.f);
}

#if defined(__has_builtin)
#if __has_builtin(__builtin_amdgcn_fdot2)
#define HAVE_FDOT2 1
#endif
#endif

// ================= fused prologue: deg count + convert_w + gstart + hgZ zero ==========
__global__ void prologue_kernel(const int* __restrict__ ei, int* __restrict__ deg,
                                const float* __restrict__ emb_W, const float* __restrict__ gat_W,
                                const float* __restrict__ ga_W1, _Float16* __restrict__ wt_emb,
                                _Float16* __restrict__ wt_gat, _Float16* __restrict__ wt_ga1,
                                const int* __restrict__ batch, int* __restrict__ gstart,
                                float* __restrict__ hgZ,
                                int E, int EE, int N, int G) {
    int i = blockIdx.x * blockDim.x + threadIdx.x;
    // degree histogram (avg ~13 atomics/address over N addresses -> uncontended)
    if (i < EE) {
        int dst = (i < E) ? ei[E + i] : (i - E);
        atomicAdd(&deg[dst], 1);
    }
    // weight transposes fp32 -> f16
    if (i < 8192) {                       // emb_W [64][128]
        int k = i >> 7, n = i & 127;
        wt_emb[n * 64 + k] = (_Float16)emb_W[i];
    } else if (i < 8192 + 49152) {        // gat_W [3][128][128]
        int j = i - 8192;
        int l = j >> 14, r = j & 16383;
        int k = r >> 7, n = r & 127;
        wt_gat[l * 16384 + n * 128 + k] = (_Float16)gat_W[j];
    } else if (i < 73728) {               // ga_W1 [128][128]
        int j = i - 57344;
        int k = j >> 7, n = j & 127;
        wt_ga1[n * 128 + k] = (_Float16)ga_W1[j];
    } else if (i < 73728 + 129) {         // hgZ zero
        hgZ[i - 73728] = 0.f;
    }
    // graph boundaries (batch sorted)
    if (i >= 100000 && i - 100000 <= G) {
        int g = i - 100000;
        int lo = 0, hi = N;
        while (lo < hi) {
            int mid = (lo + hi) >> 1;
            if (batch[mid] < g) lo = mid + 1; else hi = mid;
        }
        gstart[g] = lo;
    }
}

// ================= unified MFMA projection kernel (2 row-tiles per block) =================
// C[64 x 128] = A @ W[K x 128]; A staged via LDS (coalesced); W staged once.
// mode 0: A = fp32 x (converted during staging); embed epilogue (bias + ntype_emb -> h16)
// mode 1: A = h16; GAT proj epilogue (hp16 store + als/ald via LDS transpose)
// mode 2: A = h16; score epilogue (tanh MLP -> escore)
// Blocks with blockIdx.x >= PB run a piggybacked CSR task (overlapped with MFMA work):
//   task 1: rowptr build (in-block scan of deg + direct strided prefix sum over deg)
//   task 2: scatter (esrc fill via returning atomics on woff), grid-stride
__global__ __launch_bounds__(256) void mfma_proj_kernel(
    int mode, int K, int N,
    const _Float16* __restrict__ A16, const float* __restrict__ Af32,
    const _Float16* __restrict__ Wt,
    const float* __restrict__ bias, const float* __restrict__ nemb,
    const int* __restrict__ ntypes, _Float16* __restrict__ h16out,
    const float* __restrict__ asrc, const float* __restrict__ adst,
    _Float16* __restrict__ hp_out, float* __restrict__ als, float* __restrict__ ald,
    const float* __restrict__ w2, const float* __restrict__ b2,
    float* __restrict__ escore,
    int PB, int task, const int* __restrict__ ei2,
    const int* __restrict__ degc,
    int* __restrict__ rowptrw, int* __restrict__ woffw, int* __restrict__ esrcw,
    int E2, int EE2)
{
    __shared__ _Float16 w_lds[128 * 136];   // 34.8 KB
    __shared__ _Float16 a_lds[64 * 136];    // 17.4 KB
    int t = threadIdx.x;

    if ((int)blockIdx.x >= PB) {
        if (task == 1) {
            // ---- rowptr: exclusive prefix over deg (no partials; direct strided prefix) ----
            int b = (int)blockIdx.x - PB;
            int i = b * 256 + t;
            int v = (i < N) ? degc[i] : 0;
            // prefix of all preceding deg entries (deg is ~200KB, L2-hot; overlapped w/ MFMA blocks)
            int pe = 0;
            for (int j = t; j < (b << 8); j += 256) pe += degc[j];
#pragma unroll
            for (int m = 32; m >= 1; m >>= 1) pe += __shfl_xor(pe, m, 64);
            int* itmp  = (int*)a_lds;        // 256-int scan buffer
            int* itmp2 = itmp + 256;         // 4-int cross-wave buffer
            itmp[t] = v;
            if ((t & 63) == 0) itmp2[t >> 6] = pe;
            __syncthreads();
#pragma unroll
            for (int off = 1; off < 256; off <<= 1) {
                int x = (t >= off) ? itmp[t - off] : 0;
                __syncthreads();
                itmp[t] += x;
                __syncthreads();
            }
            pe = itmp2[0] + itmp2[1] + itmp2[2] + itmp2[3];
            int excl = itmp[t] - v + pe;
            if (i < N) { rowptrw[i] = excl; woffw[i] = excl; }
            if (b == 0 && t == 0) rowptrw[N] = EE2;
        } else {
            // ---- scatter: CSR column fill (grid-stride) ----
            int sb = (int)blockIdx.x - PB;
            int stride = ((int)gridDim.x - PB) << 8;
            for (int e = sb * 256 + t; e < EE2; e += stride) {
                int src, dst;
                if (e < E2) { src = ei2[e]; dst = ei2[E2 + e]; } else { src = dst = e - E2; }
                int slot = atomicAdd(&woffw[dst], 1);
                esrcw[slot] = src;
            }
        }
        return;
    }

    int KP = K + 8;
    int K8 = K >> 3;

    // stage W once (coalesced)
    for (int i = t; i < 128 * K8; i += 256) {
        int row = i / K8, c8 = i - row * K8;
        *(f16x8*)&w_lds[row * KP + 8 * c8] = *(const f16x8*)&Wt[(size_t)row * K + 8 * c8];
    }

    int lane = t & 63, wv = t >> 6;
    int l15 = lane & 15, quad = lane >> 4;

    for (int tile = 0; tile < 2; ++tile) {
        int n0 = blockIdx.x * 128 + tile * 64;
        if (n0 >= N) break;
        __syncthreads();   // W ready (tile 0) / previous epilogue done with a_lds
        // stage A (coalesced); mode 0 converts fp32 x in-flight
        if (mode == 0) {
            for (int i = t; i < 64 * K8; i += 256) {
                int row = i / K8, c8 = i - row * K8;
                f16x8 v = {};
                int n = n0 + row;
                if (n < N) {
                    const float4* p = (const float4*)&Af32[(size_t)n * K + 8 * c8];
                    float4 a = p[0], b = p[1];
                    v[0] = (_Float16)a.x; v[1] = (_Float16)a.y;
                    v[2] = (_Float16)a.z; v[3] = (_Float16)a.w;
                    v[4] = (_Float16)b.x; v[5] = (_Float16)b.y;
                    v[6] = (_Float16)b.z; v[7] = (_Float16)b.w;
                }
                *(f16x8*)&a_lds[row * KP + 8 * c8] = v;
            }
        } else {
            for (int i = t; i < 64 * K8; i += 256) {
                int row = i / K8, c8 = i - row * K8;
                f16x8 v = {};
                if (n0 + row < N) v = *(const f16x8*)&A16[(size_t)(n0 + row) * K + 8 * c8];
                *(f16x8*)&a_lds[row * KP + 8 * c8] = v;
            }
        }
        __syncthreads();

        f32x4 acc[8];
#pragma unroll
        for (int c = 0; c < 8; ++c) acc[c] = (f32x4){0.f, 0.f, 0.f, 0.f};

        int ksteps = K >> 5;
        for (int kk = 0; kk < ksteps; ++kk) {
            f16x8 af = *(const f16x8*)&a_lds[(wv * 16 + l15) * KP + kk * 32 + quad * 8];
#pragma unroll
            for (int c = 0; c < 8; ++c) {
                f16x8 bf = *(const f16x8*)&w_lds[(c * 16 + l15) * KP + kk * 32 + quad * 8];
                acc[c] = __builtin_amdgcn_mfma_f32_16x16x32_f16(af, bf, acc[c], 0, 0, 0);
            }
        }

        // C layout: row = wv*16 + quad*4 + r, col = c*16 + l15
        if (mode == 0) {
            float bv[8];
#pragma unroll
            for (int c = 0; c < 8; ++c) bv[c] = bias[c * 16 + l15];
            __syncthreads();
#pragma unroll
            for (int r = 0; r < 4; ++r) {
                int n = n0 + wv * 16 + quad * 4 + r;
                int nt = (n < N) ? ntypes[n] : 0;
#pragma unroll
                for (int c = 0; c < 8; ++c)
                    a_lds[(wv * 16 + quad * 4 + r) * 136 + c * 16 + l15] =
                        (_Float16)(acc[c][r] + bv[c] + nemb[nt * HID + c * 16 + l15]);
            }
            __syncthreads();
            for (int i = t; i < 64 * 16; i += 256) {
                int row = i >> 4, c8 = i & 15;
                int n = n0 + row;
                if (n < N) *(f16x8*)&h16out[(size_t)n * HID + 8 * c8] = *(const f16x8*)&a_lds[row * 136 + 8 * c8];
            }
        } else if (mode == 1) {
            __syncthreads();
#pragma unroll
            for (int c = 0; c < 8; ++c)
#pragma unroll
                for (int r = 0; r < 4; ++r)
                    a_lds[(wv * 16 + quad * 4 + r) * 136 + c * 16 + l15] = (_Float16)acc[c][r];
            __syncthreads();
            // hp16 store (coalesced 16B)
            for (int i = t; i < 64 * 16; i += 256) {
                int row = i >> 4, c8 = i & 15;
                int n = n0 + row;
                if (n < N) *(f16x8*)&hp_out[(size_t)n * HID + 8 * c8] = *(const f16x8*)&a_lds[row * 136 + 8 * c8];
            }
            // als/ald from LDS transpose: task = row*8 + head
            for (int task2 = t; task2 < 512; task2 += 256) {
                int row = task2 >> 3, hd = task2 & 7;
                int n = n0 + row;
                if (n >= N) continue;
                f16x8 v0 = *(const f16x8*)&a_lds[row * 136 + hd * 16];
                f16x8 v1 = *(const f16x8*)&a_lds[row * 136 + hd * 16 + 8];
                float va = 0.f, vd = 0.f;
#pragma unroll
                for (int j = 0; j < 8; ++j) {
                    va += (float)v0[j] * asrc[hd * 16 + j] + (float)v1[j] * asrc[hd * 16 + 8 + j];
                    vd += (float)v0[j] * adst[hd * 16 + j] + (float)v1[j] * adst[hd * 16 + 8 + j];
                }
                als[n * HEADS + hd] = va;
                ald[n * HEADS + hd] = vd;
            }
        } else {
            float b2v = b2[0];
            float treg[4] = {0.f, 0.f, 0.f, 0.f};
#pragma unroll
            for (int c = 0; c < 8; ++c) {
                float b1v = bias[c * 16 + l15];
                float w2v = w2[c * 16 + l15];
#pragma unroll
                for (int r = 0; r < 4; ++r)
                    treg[r] += fast_tanh(acc[c][r] + b1v) * w2v;
            }
#pragma unroll
            for (int r = 0; r < 4; ++r) {
                float v = treg[r];
#pragma unroll
                for (int m = 8; m >= 1; m >>= 1) v += __shfl_xor(v, m, 64);
                if (l15 == 0) {
                    int n = n0 + wv * 16 + quad * 4 + r;
                    if (n < N) escore[n] = __expf(v + b2v);
                }
            }
        }
    }
}

// ================= fused aggregate: 16 edges in flight, packed fdot2 =================
// lane = (edge-sub 0..3, chan-grp 0..15); each lane gathers 4x f16x8 per iteration.
__global__ void gat_aggregate_kernel(const int* __restrict__ rowptr, const int* __restrict__ esrc,
                                     const float* __restrict__ als, const float* __restrict__ ald,
                                     const _Float16* __restrict__ hp16, const float* __restrict__ gb,
                                     const float* __restrict__ lg, const float* __restrict__ lb,
                                     _Float16* __restrict__ h16, int N) {
    int wave = threadIdx.x >> 6;
    int lane = threadIdx.x & 63;
    int n = blockIdx.x * 4 + wave;
    if (n >= N) return;
    int esub = lane >> 4;          // 0..3
    int cg = lane & 15;            // channels cg*8 .. cg*8+7 (head cg>>1)
    int hd = cg >> 1;
    float adv = ald[n * HEADS + hd];
    int row = rowptr[n], end = rowptr[n + 1];   // end > row (self-loop)
    int last = end - 1;
    float acc[8] = {0.f, 0.f, 0.f, 0.f, 0.f, 0.f, 0.f, 0.f};
    float sw = 0.f;
    for (int base = row; base < end; base += 16) {
        int iA = base + esub;
        int iB = iA + 4, iC = iA + 8, iD = iA + 12;
        int cA = iA <= last ? iA : last;
        int cB = iB <= last ? iB : last;
        int cC = iC <= last ? iC : last;
        int cD = iD <= last ? iD : last;
        int sA = esrc[cA], sB = esrc[cB], sC = esrc[cC], sD = esrc[cD];
        f16x8 pA = *(const f16x8*)&hp16[(size_t)sA * HID + cg * 8];
        f16x8 pB = *(const f16x8*)&hp16[(size_t)sB * HID + cg * 8];
        f16x8 pC = *(const f16x8*)&hp16[(size_t)sC * HID + cg * 8];
        f16x8 pD = *(const f16x8*)&hp16[(size_t)sD * HID + cg * 8];
        float aA = als[sA * HEADS + hd];
        float aB = als[sB * HEADS + hd];
        float aC = als[sC * HEADS + hd];
        float aD = als[sD * HEADS + hd];
        float lA = aA + adv; lA = lA > 0.f ? lA : 0.2f * lA;
        float lB = aB + adv; lB = lB > 0.f ? lB : 0.2f * lB;
        float lC = aC + adv; lC = lC > 0.f ? lC : 0.2f * lC;
        float lD = aD + adv; lD = lD > 0.f ? lD : 0.2f * lD;
        float wA = __expf(lA) * ((iA < end) ? 1.f : 0.f);
        float wB = __expf(lB) * ((iB < end) ? 1.f : 0.f);
        float wC = __expf(lC) * ((iC < end) ? 1.f : 0.f);
        float wD = __expf(lD) * ((iD < end) ? 1.f : 0.f);
        sw += (wA + wB) + (wC + wD);
#ifdef HAVE_FDOT2
        f16x2 wAB; wAB[0] = (_Float16)wA; wAB[1] = (_Float16)wB;
        f16x2 wCD; wCD[0] = (_Float16)wC; wCD[1] = (_Float16)wD;
#pragma unroll
        for (int j = 0; j < 8; ++j) {
            f16x2 prAB; prAB[0] = pA[j]; prAB[1] = pB[j];
            f16x2 prCD; prCD[0] = pC[j]; prCD[1] = pD[j];
            acc[j] = __builtin_amdgcn_fdot2(prAB, wAB, acc[j], false);
            acc[j] = __builtin_amdgcn_fdot2(prCD, wCD, acc[j], false);
        }
#else
#pragma unroll
        for (int j = 0; j < 8; ++j)
            acc[j] += wA * (float)pA[j] + wB * (float)pB[j]
                    + wC * (float)pC[j] + wD * (float)pD[j];
#endif
    }
    // combine the 4 edge-subgroups (lane bits 4,5)
#pragma unroll
    for (int m = 16; m <= 32; m <<= 1) {
        sw += __shfl_xor(sw, m, 64);
#pragma unroll
        for (int j = 0; j < 8; ++j) acc[j] += __shfl_xor(acc[j], m, 64);
    }
    float inv_sw = 1.f / sw;
    float4 g0 = ((const float4*)(gb + cg * 8))[0];
    float4 g1 = ((const float4*)(gb + cg * 8))[1];
    float v[8];
    v[0] = acc[0] * inv_sw + g0.x; v[1] = acc[1] * inv_sw + g0.y;
    v[2] = acc[2] * inv_sw + g0.z; v[3] = acc[3] * inv_sw + g0.w;
    v[4] = acc[4] * inv_sw + g1.x; v[5] = acc[5] * inv_sw + g1.y;
    v[6] = acc[6] * inv_sw + g1.z; v[7] = acc[7] * inv_sw + g1.w;
    // layernorm: each channel appears 4x across the wave -> /512
    float s = 0.f;
#pragma unroll
    for (int j = 0; j < 8; ++j) s += v[j];
#pragma unroll
    for (int m = 32; m >= 1; m >>= 1) s += __shfl_xor(s, m, 64);
    float mu = s * (1.f / 512.f);
    float d[8], sq = 0.f;
#pragma unroll
    for (int j = 0; j < 8; ++j) { d[j] = v[j] - mu; sq += d[j] * d[j]; }
#pragma unroll
    for (int m = 32; m >= 1; m >>= 1) sq += __shfl_xor(sq, m, 64);
    float inv = rsqrtf(sq * (1.f / 512.f) + 1e-5f);
    float4 lg0 = ((const float4*)(lg + cg * 8))[0];
    float4 lg1 = ((const float4*)(lg + cg * 8))[1];
    float4 lb0 = ((const float4*)(lb + cg * 8))[0];
    float4 lb1 = ((const float4*)(lb + cg * 8))[1];
    float lgv[8] = {lg0.x, lg0.y, lg0.z, lg0.w, lg1.x, lg1.y, lg1.z, lg1.w};
    float lbv[8] = {lb0.x, lb0.y, lb0.z, lb0.w, lb1.x, lb1.y, lb1.z, lb1.w};
    f16x8 hold = *(const f16x8*)&h16[(size_t)n * HID + cg * 8];
    f16x8 hnew;
#pragma unroll
    for (int j = 0; j < 8; ++j) {
        float r = d[j] * inv * lgv[j] + lbv[j] + (float)hold[j];
        hnew[j] = (_Float16)(r > 0.f ? r : 0.f);
    }
    if (esub == 0) *(f16x8*)&h16[(size_t)n * HID + cg * 8] = hnew;
}

// ================= per-graph pooling (h16) =================
__global__ void pool_graph_kernel(const _Float16* __restrict__ h16, const float* __restrict__ escore,
                                  const int* __restrict__ gstart, float* __restrict__ sums,
                                  float* __restrict__ cnts, float* __restrict__ hgZ, int G) {
    int g = blockIdx.x;
    int t = threadIdx.x;               // 0..511
    int c = t & 127, grp = t >> 7;     // 4 groups
    int s = gstart[g], e = gstart[g + 1];
    float msum = 0.f, asum = 0.f, z = 0.f;
    for (int n = s + grp; n < e; n += 4) {
        float hv = (float)h16[(size_t)n * HID + c];
        float es = escore[n];
        msum += hv;
        asum += es * hv;
        if (c == 0) z += es;
    }
    __shared__ float sm[4][HID];
    __shared__ float sa[4][HID];
    __shared__ float sz[4];
    sm[grp][c] = msum;
    sa[grp][c] = asum;
    if (c == 0) sz[grp] = z;
    __syncthreads();
    if (t < HID) {
        float m = sm[0][t] + sm[1][t] + sm[2][t] + sm[3][t];
        float a = sa[0][t] + sa[1][t] + sa[2][t] + sa[3][t];
        sums[(size_t)g * HID + t] = m;
        atomicAdd(&hgZ[t], a);
    } else if (t == HID) {
        cnts[g] = (float)(e - s);
        atomicAdd(&hgZ[HID], sz[0] + sz[1] + sz[2] + sz[3]);
    }
}

// ================= classifier head =================
__global__ void head_kernel(const float* __restrict__ hgZ, const float* __restrict__ sums,
                            const float* __restrict__ cnts, const float* __restrict__ W1,
                            const float* __restrict__ b1, const float* __restrict__ W2,
                            const float* __restrict__ b2, float* __restrict__ out, int G) {
    int g = blockIdx.x;
    int t = threadIdx.x;
    __shared__ float hr[HID];
    __shared__ float part[2];
    float Z = hgZ[HID];
    float cnt = cnts[g];
    cnt = cnt > 1.f ? cnt : 1.f;
    hr[t] = hgZ[t] / Z + sums[(size_t)g * HID + t] / cnt;
    __syncthreads();
    float acc = b1[t];
#pragma unroll 8
    for (int k = 0; k < HID; ++k) acc += hr[k] * W1[k * HID + t];
    acc = acc > 0.f ? acc : 0.f;
    float v = acc * W2[t];
#pragma unroll
    for (int m = 32; m >= 1; m >>= 1) v += __shfl_xor(v, m, 64);
    if ((t & 63) == 0) part[t >> 6] = v;
    __syncthreads();
    if (t == 0) out[g] = part[0] + part[1] + b2[0];
}

extern "C" void kernel_launch(void* const* d_in, const int* in_sizes, int n_in,
                              void* d_out, int out_size, void* d_ws, size_t ws_size,
                              hipStream_t stream) {
    const float* x        = (const float*)d_in[0];
    const int*   ei       = (const int*)d_in[1];
    const int*   ntypes   = (const int*)d_in[2];
    const int*   batch    = (const int*)d_in[3];
    const float* emb_W    = (const float*)d_in[4];
    const float* emb_b    = (const float*)d_in[5];
    const float* nemb     = (const float*)d_in[6];
    const float* gat_W    = (const float*)d_in[7];
    const float* att_src  = (const float*)d_in[8];
    const float* att_dst  = (const float*)d_in[9];
    const float* gat_b    = (const float*)d_in[10];
    const float* ln_g     = (const float*)d_in[11];
    const float* ln_b     = (const float*)d_in[12];
    const float* ga_W1    = (const float*)d_in[13];
    const float* ga_b1    = (const float*)d_in[14];
    const float* ga_W2    = (const float*)d_in[15];
    const float* ga_b2    = (const float*)d_in[16];
    const float* cls_W1   = (const float*)d_in[17];
    const float* cls_b1   = (const float*)d_in[18];
    const float* cls_W2   = (const float*)d_in[19];
    const float* cls_b2   = (const float*)d_in[20];
    float* out = (float*)d_out;

    const int N  = in_sizes[2];
    const int E  = in_sizes[1] / 2;
    const int EE = E + N;
    const int G  = out_size;
    const int NB = (N + 255) / 256;

    float* ws      = (float*)d_ws;
    float* als     = ws;                               // N*8
    float* ald     = als + (size_t)N * HEADS;          // N*8
    float* escore  = ald + (size_t)N * HEADS;          // N
    float* sums    = escore + N;                       // G*128
    float* cnts    = sums + (size_t)G * HID;           // G
    float* hgZ     = cnts + G;                         // 129
    _Float16* h16  = (_Float16*)(hgZ + HID + 1);       // N*128
    _Float16* hp16 = h16 + (size_t)N * HID;            // N*128
    _Float16* wt_emb = hp16 + (size_t)N * HID;         // 128*64
    _Float16* wt_gat = wt_emb + 128 * 64;              // 3*128*128
    _Float16* wt_ga1 = wt_gat + 3 * 128 * 128;         // 128*128
    int*   rowptr  = (int*)(wt_ga1 + 128 * 128);       // N+1
    int*   woff    = rowptr + (N + 1);                 // N
    int*   deg     = woff + N;                         // N
    int*   esrc    = deg + N;                          // EE
    int*   gstart  = esrc + EE;                        // G+1

    // ---- prologue: deg zero, then fused count/converts/gstart/hgZ-zero ----
    hipMemsetAsync(deg, 0, (size_t)N * sizeof(int), stream);
    int ptot = EE;
    if (ptot < 100000 + G + 1) ptot = 100000 + G + 1;
    prologue_kernel<<<(ptot + 255) / 256, 256, 0, stream>>>(
        ei, deg, emb_W, gat_W, ga_W1, wt_emb, wt_gat, wt_ga1,
        batch, gstart, hgZ, E, EE, N, G);

    const int PB = (N + 127) / 128;   // 2 tiles of 64 per block
    int SCB = 768 - PB;               // fill remaining co-residency slots (3 blk/CU @ 52KB LDS)
    if (SCB < 128) SCB = 128;

    // ---- K1: embed projection (mode 0, fp32 x in-flight convert)  ||  rowptr build (task 1) ----
    mfma_proj_kernel<<<PB + NB, 256, 0, stream>>>(
        0, INDIM, N, nullptr, x, wt_emb, emb_b, nemb, ntypes, h16,
        nullptr, nullptr, nullptr, nullptr, nullptr, nullptr, nullptr, nullptr,
        PB, 1, nullptr, deg, rowptr, woff, nullptr, E, EE);

    // ---- K2: layer-0 GAT projection (mode 1)  ||  scatter (task 2) ----
    mfma_proj_kernel<<<PB + SCB, 256, 0, stream>>>(
        1, HID, N, h16, nullptr, wt_gat,
        nullptr, nullptr, nullptr, nullptr,
        att_src, att_dst, hp16, als, ald, nullptr, nullptr, nullptr,
        PB, 2, ei, nullptr, nullptr, woff, esrc, E, EE);

    gat_aggregate_kernel<<<(N + 3) / 4, 256, 0, stream>>>(
        rowptr, esrc, als, ald, hp16,
        gat_b, ln_g, ln_b, h16, N);

    for (int l = 1; l < 3; ++l) {
        mfma_proj_kernel<<<PB, 256, 0, stream>>>(
            1, HID, N, h16, nullptr, wt_gat + (size_t)l * HID * HID,
            nullptr, nullptr, nullptr, nullptr,
            att_src + l * HID, att_dst + l * HID,
            hp16, als, ald, nullptr, nullptr, nullptr,
            PB, 0, nullptr, nullptr, nullptr, nullptr, nullptr, 0, 0);
        gat_aggregate_kernel<<<(N + 3) / 4, 256, 0, stream>>>(
            rowptr, esrc, als, ald, hp16,
            gat_b + l * HID, ln_g + l * HID, ln_b + l * HID, h16, N);
    }

    mfma_proj_kernel<<<PB, 256, 0, stream>>>(
        2, HID, N, h16, nullptr, wt_ga1, ga_b1, nullptr, nullptr, nullptr,
        nullptr, nullptr, nullptr, nullptr, nullptr, ga_W2, ga_b2, escore,
        PB, 0, nullptr, nullptr, nullptr, nullptr, nullptr, 0, 0);

    pool_graph_kernel<<<G, 512, 0, stream>>>(h16, escore, gstart, sums, cnts, hgZ, G);
    head_kernel<<<G, 128, 0, stream>>>(hgZ, sums, cnts, cls_W1, cls_b1, cls_W2, cls_b2, out, G);
}

// Round 10
// 391.485 us; speedup vs baseline: 2.3384x; 1.0390x over previous
//
#include <hip/hip_runtime.h>
#include <hip/hip_bf16.h>
#include <math.h>

#define HID 128
#define HEADS 8
#define INDIM 64

typedef _Float16 f16x8 __attribute__((ext_vector_type(8)));
typedef _Float16 f16x4 __attribute__((ext_vector_type(4)));
typedef _Float16 f16x2 __attribute__((ext_vector_type(2)));
typedef float f32x4 __attribute__((ext_vector_type(4)));

__device__ __forceinline__ float fast_tanh(float x) {
    return 1.f - 2.f / (__expf(2.f * x) + 1.f);
}

#if defined(__has_builtin)
#if __has_builtin(__builtin_amdgcn_fdot2)
#define HAVE_FDOT2 1
#endif
#endif

// ================= fused prologue: deg count + convert_w + gstart + hgZ4 zero ==========
__global__ void prologue_kernel(const int* __restrict__ ei, int* __restrict__ deg,
                                const float* __restrict__ emb_W, const float* __restrict__ gat_W,
                                const float* __restrict__ ga_W1, _Float16* __restrict__ wt_emb,
                                _Float16* __restrict__ wt_gat, _Float16* __restrict__ wt_ga1,
                                const int* __restrict__ batch, int* __restrict__ gstart,
                                float* __restrict__ hgZ4,
                                int E, int EE, int N, int G) {
    int i = blockIdx.x * blockDim.x + threadIdx.x;
    // degree histogram (avg ~13 atomics/address over N addresses -> uncontended)
    if (i < EE) {
        int dst = (i < E) ? ei[E + i] : (i - E);
        atomicAdd(&deg[dst], 1);
    }
    // weight transposes fp32 -> f16
    if (i < 8192) {                       // emb_W [64][128]
        int k = i >> 7, n = i & 127;
        wt_emb[n * 64 + k] = (_Float16)emb_W[i];
    } else if (i < 8192 + 49152) {        // gat_W [3][128][128]
        int j = i - 8192;
        int l = j >> 14, r = j & 16383;
        int k = r >> 7, n = r & 127;
        wt_gat[l * 16384 + n * 128 + k] = (_Float16)gat_W[j];
    } else if (i < 73728) {               // ga_W1 [128][128]
        int j = i - 57344;
        int k = j >> 7, n = j & 127;
        wt_ga1[n * 128 + k] = (_Float16)ga_W1[j];
    } else if (i < 73728 + 544) {         // hgZ4 zero (4 shadow copies x 136)
        hgZ4[i - 73728] = 0.f;
    }
    // graph boundaries (batch sorted)
    if (i >= 100000 && i - 100000 <= G) {
        int g = i - 100000;
        int lo = 0, hi = N;
        while (lo < hi) {
            int mid = (lo + hi) >> 1;
            if (batch[mid] < g) lo = mid + 1; else hi = mid;
        }
        gstart[g] = lo;
    }
}

// ================= unified MFMA projection kernel (2 row-tiles per block) =================
// C[64 x 128] = A @ W[K x 128]; A staged via LDS (coalesced); W staged once.
// mode 0: A = fp32 x (converted during staging); embed epilogue (bias + ntype_emb -> h16)
// mode 1: A = h16; GAT proj epilogue (hp16 store + als/ald via LDS transpose)
// mode 2: A = h16; score epilogue (tanh MLP -> escore)
// Blocks with blockIdx.x >= PB run a piggybacked CSR task (overlapped with MFMA work):
//   task 1: rowptr build (in-block scan of deg + direct strided prefix sum over deg)
//   task 2: scatter (esrc fill via returning atomics on woff), grid-stride
__global__ __launch_bounds__(256) void mfma_proj_kernel(
    int mode, int K, int N,
    const _Float16* __restrict__ A16, const float* __restrict__ Af32,
    const _Float16* __restrict__ Wt,
    const float* __restrict__ bias, const float* __restrict__ nemb,
    const int* __restrict__ ntypes, _Float16* __restrict__ h16out,
    const float* __restrict__ asrc, const float* __restrict__ adst,
    _Float16* __restrict__ hp_out, float* __restrict__ als, float* __restrict__ ald,
    const float* __restrict__ w2, const float* __restrict__ b2,
    float* __restrict__ escore,
    int PB, int task, const int* __restrict__ ei2,
    const int* __restrict__ degc,
    int* __restrict__ rowptrw, int* __restrict__ woffw, int* __restrict__ esrcw,
    int E2, int EE2)
{
    __shared__ _Float16 w_lds[128 * 136];   // 34.8 KB
    __shared__ _Float16 a_lds[64 * 136];    // 17.4 KB
    int t = threadIdx.x;

    if ((int)blockIdx.x >= PB) {
        if (task == 1) {
            // ---- rowptr: exclusive prefix over deg (no partials; direct strided prefix) ----
            int b = (int)blockIdx.x - PB;
            int i = b * 256 + t;
            int v = (i < N) ? degc[i] : 0;
            // prefix of all preceding deg entries (deg is ~200KB, L2-hot; overlapped w/ MFMA blocks)
            int pe = 0;
            for (int j = t; j < (b << 8); j += 256) pe += degc[j];
#pragma unroll
            for (int m = 32; m >= 1; m >>= 1) pe += __shfl_xor(pe, m, 64);
            int* itmp  = (int*)a_lds;        // 256-int scan buffer
            int* itmp2 = itmp + 256;         // 4-int cross-wave buffer
            itmp[t] = v;
            if ((t & 63) == 0) itmp2[t >> 6] = pe;
            __syncthreads();
#pragma unroll
            for (int off = 1; off < 256; off <<= 1) {
                int x = (t >= off) ? itmp[t - off] : 0;
                __syncthreads();
                itmp[t] += x;
                __syncthreads();
            }
            pe = itmp2[0] + itmp2[1] + itmp2[2] + itmp2[3];
            int excl = itmp[t] - v + pe;
            if (i < N) { rowptrw[i] = excl; woffw[i] = excl; }
            if (b == 0 && t == 0) rowptrw[N] = EE2;
        } else {
            // ---- scatter: CSR column fill (grid-stride) ----
            int sb = (int)blockIdx.x - PB;
            int stride = ((int)gridDim.x - PB) << 8;
            for (int e = sb * 256 + t; e < EE2; e += stride) {
                int src, dst;
                if (e < E2) { src = ei2[e]; dst = ei2[E2 + e]; } else { src = dst = e - E2; }
                int slot = atomicAdd(&woffw[dst], 1);
                esrcw[slot] = src;
            }
        }
        return;
    }

    int KP = K + 8;
    int K8 = K >> 3;

    // stage W once (coalesced)
    for (int i = t; i < 128 * K8; i += 256) {
        int row = i / K8, c8 = i - row * K8;
        *(f16x8*)&w_lds[row * KP + 8 * c8] = *(const f16x8*)&Wt[(size_t)row * K + 8 * c8];
    }

    int lane = t & 63, wv = t >> 6;
    int l15 = lane & 15, quad = lane >> 4;

    for (int tile = 0; tile < 2; ++tile) {
        int n0 = blockIdx.x * 128 + tile * 64;
        if (n0 >= N) break;
        __syncthreads();   // W ready (tile 0) / previous epilogue done with a_lds
        // stage A (coalesced); mode 0 converts fp32 x in-flight
        if (mode == 0) {
            for (int i = t; i < 64 * K8; i += 256) {
                int row = i / K8, c8 = i - row * K8;
                f16x8 v = {};
                int n = n0 + row;
                if (n < N) {
                    const float4* p = (const float4*)&Af32[(size_t)n * K + 8 * c8];
                    float4 a = p[0], b = p[1];
                    v[0] = (_Float16)a.x; v[1] = (_Float16)a.y;
                    v[2] = (_Float16)a.z; v[3] = (_Float16)a.w;
                    v[4] = (_Float16)b.x; v[5] = (_Float16)b.y;
                    v[6] = (_Float16)b.z; v[7] = (_Float16)b.w;
                }
                *(f16x8*)&a_lds[row * KP + 8 * c8] = v;
            }
        } else {
            for (int i = t; i < 64 * K8; i += 256) {
                int row = i / K8, c8 = i - row * K8;
                f16x8 v = {};
                if (n0 + row < N) v = *(const f16x8*)&A16[(size_t)(n0 + row) * K + 8 * c8];
                *(f16x8*)&a_lds[row * KP + 8 * c8] = v;
            }
        }
        __syncthreads();

        f32x4 acc[8];
#pragma unroll
        for (int c = 0; c < 8; ++c) acc[c] = (f32x4){0.f, 0.f, 0.f, 0.f};

        int ksteps = K >> 5;
        for (int kk = 0; kk < ksteps; ++kk) {
            f16x8 af = *(const f16x8*)&a_lds[(wv * 16 + l15) * KP + kk * 32 + quad * 8];
#pragma unroll
            for (int c = 0; c < 8; ++c) {
                f16x8 bf = *(const f16x8*)&w_lds[(c * 16 + l15) * KP + kk * 32 + quad * 8];
                acc[c] = __builtin_amdgcn_mfma_f32_16x16x32_f16(af, bf, acc[c], 0, 0, 0);
            }
        }

        // C layout: row = wv*16 + quad*4 + r, col = c*16 + l15
        if (mode == 0) {
            float bv[8];
#pragma unroll
            for (int c = 0; c < 8; ++c) bv[c] = bias[c * 16 + l15];
            __syncthreads();
#pragma unroll
            for (int r = 0; r < 4; ++r) {
                int n = n0 + wv * 16 + quad * 4 + r;
                int nt = (n < N) ? ntypes[n] : 0;
#pragma unroll
                for (int c = 0; c < 8; ++c)
                    a_lds[(wv * 16 + quad * 4 + r) * 136 + c * 16 + l15] =
                        (_Float16)(acc[c][r] + bv[c] + nemb[nt * HID + c * 16 + l15]);
            }
            __syncthreads();
            for (int i = t; i < 64 * 16; i += 256) {
                int row = i >> 4, c8 = i & 15;
                int n = n0 + row;
                if (n < N) *(f16x8*)&h16out[(size_t)n * HID + 8 * c8] = *(const f16x8*)&a_lds[row * 136 + 8 * c8];
            }
        } else if (mode == 1) {
            __syncthreads();
#pragma unroll
            for (int c = 0; c < 8; ++c)
#pragma unroll
                for (int r = 0; r < 4; ++r)
                    a_lds[(wv * 16 + quad * 4 + r) * 136 + c * 16 + l15] = (_Float16)acc[c][r];
            __syncthreads();
            // hp16 store (coalesced 16B)
            for (int i = t; i < 64 * 16; i += 256) {
                int row = i >> 4, c8 = i & 15;
                int n = n0 + row;
                if (n < N) *(f16x8*)&hp_out[(size_t)n * HID + 8 * c8] = *(const f16x8*)&a_lds[row * 136 + 8 * c8];
            }
            // als/ald from LDS transpose: task = row*8 + head
            for (int task2 = t; task2 < 512; task2 += 256) {
                int row = task2 >> 3, hd = task2 & 7;
                int n = n0 + row;
                if (n >= N) continue;
                f16x8 v0 = *(const f16x8*)&a_lds[row * 136 + hd * 16];
                f16x8 v1 = *(const f16x8*)&a_lds[row * 136 + hd * 16 + 8];
                float va = 0.f, vd = 0.f;
#pragma unroll
                for (int j = 0; j < 8; ++j) {
                    va += (float)v0[j] * asrc[hd * 16 + j] + (float)v1[j] * asrc[hd * 16 + 8 + j];
                    vd += (float)v0[j] * adst[hd * 16 + j] + (float)v1[j] * adst[hd * 16 + 8 + j];
                }
                als[n * HEADS + hd] = va;
                ald[n * HEADS + hd] = vd;
            }
        } else {
            float b2v = b2[0];
            float treg[4] = {0.f, 0.f, 0.f, 0.f};
#pragma unroll
            for (int c = 0; c < 8; ++c) {
                float b1v = bias[c * 16 + l15];
                float w2v = w2[c * 16 + l15];
#pragma unroll
                for (int r = 0; r < 4; ++r)
                    treg[r] += fast_tanh(acc[c][r] + b1v) * w2v;
            }
#pragma unroll
            for (int r = 0; r < 4; ++r) {
                float v = treg[r];
#pragma unroll
                for (int m = 8; m >= 1; m >>= 1) v += __shfl_xor(v, m, 64);
                if (l15 == 0) {
                    int n = n0 + wv * 16 + quad * 4 + r;
                    if (n < N) escore[n] = __expf(v + b2v);
                }
            }
        }
    }
}

// ================= fused aggregate: 16 edges in flight, packed fdot2 =================
// lane = (edge-sub 0..3, chan-grp 0..15); each lane gathers 4x f16x8 per iteration.
__global__ void gat_aggregate_kernel(const int* __restrict__ rowptr, const int* __restrict__ esrc,
                                     const float* __restrict__ als, const float* __restrict__ ald,
                                     const _Float16* __restrict__ hp16, const float* __restrict__ gb,
                                     const float* __restrict__ lg, const float* __restrict__ lb,
                                     _Float16* __restrict__ h16, int N) {
    int wave = threadIdx.x >> 6;
    int lane = threadIdx.x & 63;
    int n = blockIdx.x * 4 + wave;
    if (n >= N) return;
    int esub = lane >> 4;          // 0..3
    int cg = lane & 15;            // channels cg*8 .. cg*8+7 (head cg>>1)
    int hd = cg >> 1;
    float adv = ald[n * HEADS + hd];
    int row = rowptr[n], end = rowptr[n + 1];   // end > row (self-loop)
    int last = end - 1;
    float acc[8] = {0.f, 0.f, 0.f, 0.f, 0.f, 0.f, 0.f, 0.f};
    float sw = 0.f;
    for (int base = row; base < end; base += 16) {
        int iA = base + esub;
        int iB = iA + 4, iC = iA + 8, iD = iA + 12;
        int cA = iA <= last ? iA : last;
        int cB = iB <= last ? iB : last;
        int cC = iC <= last ? iC : last;
        int cD = iD <= last ? iD : last;
        int sA = esrc[cA], sB = esrc[cB], sC = esrc[cC], sD = esrc[cD];
        f16x8 pA = *(const f16x8*)&hp16[(size_t)sA * HID + cg * 8];
        f16x8 pB = *(const f16x8*)&hp16[(size_t)sB * HID + cg * 8];
        f16x8 pC = *(const f16x8*)&hp16[(size_t)sC * HID + cg * 8];
        f16x8 pD = *(const f16x8*)&hp16[(size_t)sD * HID + cg * 8];
        float aA = als[sA * HEADS + hd];
        float aB = als[sB * HEADS + hd];
        float aC = als[sC * HEADS + hd];
        float aD = als[sD * HEADS + hd];
        float lA = aA + adv; lA = lA > 0.f ? lA : 0.2f * lA;
        float lB = aB + adv; lB = lB > 0.f ? lB : 0.2f * lB;
        float lC = aC + adv; lC = lC > 0.f ? lC : 0.2f * lC;
        float lD = aD + adv; lD = lD > 0.f ? lD : 0.2f * lD;
        float wA = __expf(lA) * ((iA < end) ? 1.f : 0.f);
        float wB = __expf(lB) * ((iB < end) ? 1.f : 0.f);
        float wC = __expf(lC) * ((iC < end) ? 1.f : 0.f);
        float wD = __expf(lD) * ((iD < end) ? 1.f : 0.f);
        sw += (wA + wB) + (wC + wD);
#ifdef HAVE_FDOT2
        f16x2 wAB; wAB[0] = (_Float16)wA; wAB[1] = (_Float16)wB;
        f16x2 wCD; wCD[0] = (_Float16)wC; wCD[1] = (_Float16)wD;
#pragma unroll
        for (int j = 0; j < 8; ++j) {
            f16x2 prAB; prAB[0] = pA[j]; prAB[1] = pB[j];
            f16x2 prCD; prCD[0] = pC[j]; prCD[1] = pD[j];
            acc[j] = __builtin_amdgcn_fdot2(prAB, wAB, acc[j], false);
            acc[j] = __builtin_amdgcn_fdot2(prCD, wCD, acc[j], false);
        }
#else
#pragma unroll
        for (int j = 0; j < 8; ++j)
            acc[j] += wA * (float)pA[j] + wB * (float)pB[j]
                    + wC * (float)pC[j] + wD * (float)pD[j];
#endif
    }
    // combine the 4 edge-subgroups (lane bits 4,5)
#pragma unroll
    for (int m = 16; m <= 32; m <<= 1) {
        sw += __shfl_xor(sw, m, 64);
#pragma unroll
        for (int j = 0; j < 8; ++j) acc[j] += __shfl_xor(acc[j], m, 64);
    }
    float inv_sw = 1.f / sw;
    float4 g0 = ((const float4*)(gb + cg * 8))[0];
    float4 g1 = ((const float4*)(gb + cg * 8))[1];
    float v[8];
    v[0] = acc[0] * inv_sw + g0.x; v[1] = acc[1] * inv_sw + g0.y;
    v[2] = acc[2] * inv_sw + g0.z; v[3] = acc[3] * inv_sw + g0.w;
    v[4] = acc[4] * inv_sw + g1.x; v[5] = acc[5] * inv_sw + g1.y;
    v[6] = acc[6] * inv_sw + g1.z; v[7] = acc[7] * inv_sw + g1.w;
    // layernorm: each channel appears 4x across the wave -> /512
    float s = 0.f;
#pragma unroll
    for (int j = 0; j < 8; ++j) s += v[j];
#pragma unroll
    for (int m = 32; m >= 1; m >>= 1) s += __shfl_xor(s, m, 64);
    float mu = s * (1.f / 512.f);
    float d[8], sq = 0.f;
#pragma unroll
    for (int j = 0; j < 8; ++j) { d[j] = v[j] - mu; sq += d[j] * d[j]; }
#pragma unroll
    for (int m = 32; m >= 1; m >>= 1) sq += __shfl_xor(sq, m, 64);
    float inv = rsqrtf(sq * (1.f / 512.f) + 1e-5f);
    float4 lg0 = ((const float4*)(lg + cg * 8))[0];
    float4 lg1 = ((const float4*)(lg + cg * 8))[1];
    float4 lb0 = ((const float4*)(lb + cg * 8))[0];
    float4 lb1 = ((const float4*)(lb + cg * 8))[1];
    float lgv[8] = {lg0.x, lg0.y, lg0.z, lg0.w, lg1.x, lg1.y, lg1.z, lg1.w};
    float lbv[8] = {lb0.x, lb0.y, lb0.z, lb0.w, lb1.x, lb1.y, lb1.z, lb1.w};
    f16x8 hold = *(const f16x8*)&h16[(size_t)n * HID + cg * 8];
    f16x8 hnew;
#pragma unroll
    for (int j = 0; j < 8; ++j) {
        float r = d[j] * inv * lgv[j] + lbv[j] + (float)hold[j];
        hnew[j] = (_Float16)(r > 0.f ? r : 0.f);
    }
    if (esub == 0) *(f16x8*)&h16[(size_t)n * HID + cg * 8] = hnew;
}

// ================= per-graph pooling (vectorized f16x8 loads, 4-way shadowed hgZ) ======
// thread = (chunk 0..15: 8 channels, rg 0..31: row group). 16 B/lane loads (G13) vs
// the old 2 B scalar loads; hgZ atomics spread over 4 shadow copies (contention /4).
__global__ void pool_graph_kernel(const _Float16* __restrict__ h16, const float* __restrict__ escore,
                                  const int* __restrict__ gstart, float* __restrict__ sums,
                                  float* __restrict__ cnts, float* __restrict__ hgZ4, int G) {
    int g = blockIdx.x;
    int t = threadIdx.x;               // 0..511
    int chunk = t & 15;                // 8-channel chunk
    int rg = t >> 4;                   // 0..31 row group
    int s = gstart[g], e = gstart[g + 1];
    float msum[8] = {0.f, 0.f, 0.f, 0.f, 0.f, 0.f, 0.f, 0.f};
    float asum[8] = {0.f, 0.f, 0.f, 0.f, 0.f, 0.f, 0.f, 0.f};
    float z = 0.f;
    for (int n = s + rg; n < e; n += 32) {
        f16x8 hv = *(const f16x8*)&h16[(size_t)n * HID + chunk * 8];
        float es = escore[n];
#pragma unroll
        for (int j = 0; j < 8; ++j) {
            float h = (float)hv[j];
            msum[j] += h;
            asum[j] += es * h;
        }
        if (chunk == 0) z += es;
    }
    __shared__ float sm[32][HID];      // 16 KB
    __shared__ float sa[32][HID];      // 16 KB
    __shared__ float szs[32];
#pragma unroll
    for (int j = 0; j < 8; ++j) {
        sm[rg][chunk * 8 + j] = msum[j];
        sa[rg][chunk * 8 + j] = asum[j];
    }
    if (chunk == 0) szs[rg] = z;
    __syncthreads();
    if (t < HID) {
        float m = 0.f, a = 0.f;
#pragma unroll
        for (int r = 0; r < 32; ++r) { m += sm[r][t]; a += sa[r][t]; }
        sums[(size_t)g * HID + t] = m;
        atomicAdd(&hgZ4[(g & 3) * 136 + t], a);
    } else if (t == HID) {
        float zz = 0.f;
#pragma unroll
        for (int r = 0; r < 32; ++r) zz += szs[r];
        cnts[g] = (float)(e - s);
        atomicAdd(&hgZ4[(g & 3) * 136 + HID], zz);
    }
}

// ================= classifier head (sums the 4 hgZ shadow copies) =================
__global__ void head_kernel(const float* __restrict__ hgZ4, const float* __restrict__ sums,
                            const float* __restrict__ cnts, const float* __restrict__ W1,
                            const float* __restrict__ b1, const float* __restrict__ W2,
                            const float* __restrict__ b2, float* __restrict__ out, int G) {
    int g = blockIdx.x;
    int t = threadIdx.x;
    __shared__ float hr[HID];
    __shared__ float part[2];
    float Z = hgZ4[HID] + hgZ4[136 + HID] + hgZ4[272 + HID] + hgZ4[408 + HID];
    float cnt = cnts[g];
    cnt = cnt > 1.f ? cnt : 1.f;
    float att = hgZ4[t] + hgZ4[136 + t] + hgZ4[272 + t] + hgZ4[408 + t];
    hr[t] = att / Z + sums[(size_t)g * HID + t] / cnt;
    __syncthreads();
    float acc = b1[t];
#pragma unroll 8
    for (int k = 0; k < HID; ++k) acc += hr[k] * W1[k * HID + t];
    acc = acc > 0.f ? acc : 0.f;
    float v = acc * W2[t];
#pragma unroll
    for (int m = 32; m >= 1; m >>= 1) v += __shfl_xor(v, m, 64);
    if ((t & 63) == 0) part[t >> 6] = v;
    __syncthreads();
    if (t == 0) out[g] = part[0] + part[1] + b2[0];
}

extern "C" void kernel_launch(void* const* d_in, const int* in_sizes, int n_in,
                              void* d_out, int out_size, void* d_ws, size_t ws_size,
                              hipStream_t stream) {
    const float* x        = (const float*)d_in[0];
    const int*   ei       = (const int*)d_in[1];
    const int*   ntypes   = (const int*)d_in[2];
    const int*   batch    = (const int*)d_in[3];
    const float* emb_W    = (const float*)d_in[4];
    const float* emb_b    = (const float*)d_in[5];
    const float* nemb     = (const float*)d_in[6];
    const float* gat_W    = (const float*)d_in[7];
    const float* att_src  = (const float*)d_in[8];
    const float* att_dst  = (const float*)d_in[9];
    const float* gat_b    = (const float*)d_in[10];
    const float* ln_g     = (const float*)d_in[11];
    const float* ln_b     = (const float*)d_in[12];
    const float* ga_W1    = (const float*)d_in[13];
    const float* ga_b1    = (const float*)d_in[14];
    const float* ga_W2    = (const float*)d_in[15];
    const float* ga_b2    = (const float*)d_in[16];
    const float* cls_W1   = (const float*)d_in[17];
    const float* cls_b1   = (const float*)d_in[18];
    const float* cls_W2   = (const float*)d_in[19];
    const float* cls_b2   = (const float*)d_in[20];
    float* out = (float*)d_out;

    const int N  = in_sizes[2];
    const int E  = in_sizes[1] / 2;
    const int EE = E + N;
    const int G  = out_size;
    const int NB = (N + 255) / 256;

    float* ws      = (float*)d_ws;
    float* als     = ws;                               // N*8
    float* ald     = als + (size_t)N * HEADS;          // N*8
    float* escore  = ald + (size_t)N * HEADS;          // N
    float* sums    = escore + N;                       // G*128
    float* cnts    = sums + (size_t)G * HID;           // G
    float* hgZ4    = cnts + G;                         // 4*136 shadow copies
    _Float16* h16  = (_Float16*)(hgZ4 + 544);          // N*128 (16B-aligned)
    _Float16* hp16 = h16 + (size_t)N * HID;            // N*128
    _Float16* wt_emb = hp16 + (size_t)N * HID;         // 128*64
    _Float16* wt_gat = wt_emb + 128 * 64;              // 3*128*128
    _Float16* wt_ga1 = wt_gat + 3 * 128 * 128;         // 128*128
    int*   rowptr  = (int*)(wt_ga1 + 128 * 128);       // N+1
    int*   woff    = rowptr + (N + 1);                 // N
    int*   deg     = woff + N;                         // N
    int*   esrc    = deg + N;                          // EE
    int*   gstart  = esrc + EE;                        // G+1

    // ---- prologue: deg zero, then fused count/converts/gstart/hgZ4-zero ----
    hipMemsetAsync(deg, 0, (size_t)N * sizeof(int), stream);
    int ptot = EE;
    if (ptot < 100000 + G + 1) ptot = 100000 + G + 1;
    prologue_kernel<<<(ptot + 255) / 256, 256, 0, stream>>>(
        ei, deg, emb_W, gat_W, ga_W1, wt_emb, wt_gat, wt_ga1,
        batch, gstart, hgZ4, E, EE, N, G);

    const int PB = (N + 127) / 128;   // 2 tiles of 64 per block
    int SCB = 768 - PB;               // fill remaining co-residency slots (3 blk/CU @ 52KB LDS)
    if (SCB < 128) SCB = 128;

    // ---- K1: embed projection (mode 0, fp32 x in-flight convert)  ||  rowptr build (task 1) ----
    mfma_proj_kernel<<<PB + NB, 256, 0, stream>>>(
        0, INDIM, N, nullptr, x, wt_emb, emb_b, nemb, ntypes, h16,
        nullptr, nullptr, nullptr, nullptr, nullptr, nullptr, nullptr, nullptr,
        PB, 1, nullptr, deg, rowptr, woff, nullptr, E, EE);

    // ---- K2: layer-0 GAT projection (mode 1)  ||  scatter (task 2) ----
    mfma_proj_kernel<<<PB + SCB, 256, 0, stream>>>(
        1, HID, N, h16, nullptr, wt_gat,
        nullptr, nullptr, nullptr, nullptr,
        att_src, att_dst, hp16, als, ald, nullptr, nullptr, nullptr,
        PB, 2, ei, nullptr, nullptr, woff, esrc, E, EE);

    gat_aggregate_kernel<<<(N + 3) / 4, 256, 0, stream>>>(
        rowptr, esrc, als, ald, hp16,
        gat_b, ln_g, ln_b, h16, N);

    for (int l = 1; l < 3; ++l) {
        mfma_proj_kernel<<<PB, 256, 0, stream>>>(
            1, HID, N, h16, nullptr, wt_gat + (size_t)l * HID * HID,
            nullptr, nullptr, nullptr, nullptr,
            att_src + l * HID, att_dst + l * HID,
            hp16, als, ald, nullptr, nullptr, nullptr,
            PB, 0, nullptr, nullptr, nullptr, nullptr, nullptr, 0, 0);
        gat_aggregate_kernel<<<(N + 3) / 4, 256, 0, stream>>>(
            rowptr, esrc, als, ald, hp16,
            gat_b + l * HID, ln_g + l * HID, ln_b + l * HID, h16, N);
    }

    mfma_proj_kernel<<<PB, 256, 0, stream>>>(
        2, HID, N, h16, nullptr, wt_ga1, ga_b1, nullptr, nullptr, nullptr,
        nullptr, nullptr, nullptr, nullptr, nullptr, ga_W2, ga_b2, escore,
        PB, 0, nullptr, nullptr, nullptr, nullptr, nullptr, 0, 0);

    pool_graph_kernel<<<G, 512, 0, stream>>>(h16, escore, gstart, sums, cnts, hgZ4, G);
    head_kernel<<<G, 128, 0, stream>>>(hgZ4, sums, cnts, cls_W1, cls_b1, cls_W2, cls_b2, out, G);
}